// Round 8
// baseline (36.284 us; speedup 1.0000x reference)
//
#include <hip/hip_runtime.h>
#include <hip/hip_bf16.h>

#define N_TOT 2048
#define M_DIM 64
#define O_DIM 128
#define NT 8    // neurons per block
#define OC 32   // o-columns per block

typedef __bf16 bf16x8 __attribute__((ext_vector_type(8)));
typedef float f32x4 __attribute__((ext_vector_type(4)));

// Grid 1024 = 256 n-groups x 4 o-quarters. Block 256 thr (4 waves), 32 KiB LDS
// -> 4 independent blocks/CU, ONE barrier per block lifetime. w1 staged exactly
// once device-wide (o-split); x re-read by o-siblings from same-XCD L2.
// Wave w computes neurons n0+2w, n0+2w+1 over all 64 b-rows, 32 o-cols.
__global__ __launch_bounds__(256, 4) void superlinear_mfma(
    const float* __restrict__ x, const float* __restrict__ w1,
    const float* __restrict__ b1, float* __restrict__ out)
{
    // bf16 W tile [nn][ol][m] (m innermost), XOR-swizzled. 32 KiB.
    __shared__ unsigned char wlds[NT * OC * M_DIM * 2];

    const int tid  = threadIdx.x;
    const int lane = tid & 63;
    const int wave = tid >> 6;   // 0..3

    // XCD swizzle (1024 % 8 == 0 -> bijective). Consecutive swz on one XCD:
    // the 4 o-quarters of each n-group are dispatch-adjacent on the same XCD,
    // so their shared x rows hit that XCD's L2.
    const int bid = blockIdx.x;
    const int swz = (bid & 7) * 128 + (bid >> 3);
    const int nq  = swz >> 2;
    const int oq  = swz & 3;
    const int n0  = nq * NT;
    const int o0  = oq * OC;

    const int col = lane & 15;   // o (and b-row) index within 16-tile
    const int kg  = lane >> 4;   // k-group (8 bf16)

    // staging decomposition: thread -> (n-half, o-local, 16 m-rows)
    const int half = tid & 1;
    const int ol   = (tid >> 1) & 31;
    const int mseg = tid >> 6;            // m-rows mseg*16 .. +15

    const size_t MSTR = (size_t)O_DIM * N_TOT;   // w1 m-stride (floats)

    // ---- Stage issue: 16 float4 (w1[m16][o0+ol][n0..+8] slice) ----
    float4 sr[16];
    {
        const float* gp = w1 + ((size_t)(mseg * 16) * O_DIM + (o0 + ol)) * N_TOT
                             + n0 + half * 4;
        #pragma unroll
        for (int mm = 0; mm < 16; ++mm)
            sr[mm] = *(const float4*)(gp + (size_t)mm * MSTR);
    }

    // bias: 2 neurons x 2 o-tiles
    float bv[2][2];
    #pragma unroll
    for (int n2 = 0; n2 < 2; ++n2)
        #pragma unroll
        for (int ot = 0; ot < 2; ++ot)
            bv[n2][ot] = b1[(size_t)(n0 + wave * 2 + n2) * O_DIM + o0 + ot * 16 + col];

    // x loads for bt=0 issued before the staging writes (deep in vm queue)
    float4 xr[8];
    auto load_x = [&](int bt, float4* r) {
        #pragma unroll
        for (int n2 = 0; n2 < 2; ++n2)
            #pragma unroll
            for (int kc = 0; kc < 2; ++kc) {
                const float* xp = x
                    + ((size_t)(bt * 16 + col) * N_TOT + (n0 + wave * 2 + n2)) * M_DIM
                    + kc * 32 + kg * 8;
                r[n2 * 4 + kc * 2 + 0] = *(const float4*)xp;
                r[n2 * 4 + kc * 2 + 1] = *(const float4*)(xp + 4);
            }
    };
    load_x(0, xr);

    // ---- Stage write: convert + 8x ds_write_b128, layout [nn][ol][m] ----
    #pragma unroll
    for (int j = 0; j < 4; ++j) {
        int nn = half * 4 + j;
        #pragma unroll
        for (int q = 0; q < 2; ++q) {
            bf16x8 v;
            #pragma unroll
            for (int t = 0; t < 8; ++t)
                v[t] = (__bf16)(((const float*)&sr[q * 8 + t])[j]);
            unsigned addr = (unsigned)(nn * 4096 + ol * 128 + mseg * 32 + q * 16);
            addr ^= (unsigned)((ol & 7) << 4);   // bank swizzle bits 4-6
            *(bf16x8*)(wlds + addr) = v;
        }
    }

    __syncthreads();   // the only barrier

    // ---- Compute: 4 b-tiles; per bt: convert x -> issue next x -> MFMA -> store
    const unsigned sw = (unsigned)(col & 7) << 4;
    #pragma unroll
    for (int bt = 0; bt < 4; ++bt) {
        // convert current x (frees xr), then issue next bt's x into xr
        bf16x8 af[2][2];
        #pragma unroll
        for (int n2 = 0; n2 < 2; ++n2)
            #pragma unroll
            for (int kc = 0; kc < 2; ++kc) {
                const float* lp = (const float*)&xr[n2 * 4 + kc * 2 + 0];
                const float* hp = (const float*)&xr[n2 * 4 + kc * 2 + 1];
                bf16x8 v;
                #pragma unroll
                for (int t = 0; t < 4; ++t) {
                    v[t]     = (__bf16)lp[t];
                    v[4 + t] = (__bf16)hp[t];
                }
                af[n2][kc] = v;
            }
        if (bt < 3) load_x(bt + 1, xr);   // in flight under MFMA+stores

        #pragma unroll
        for (int n2 = 0; n2 < 2; ++n2) {
            int nn = wave * 2 + n2;
            int n  = n0 + nn;
            f32x4 aa[2];
            #pragma unroll
            for (int ot = 0; ot < 2; ++ot) {
                // logical addr first (bit 6 clean), swizzle last
                unsigned la = (unsigned)(nn * 4096 + (ot * 16 + col) * 128 + kg * 16);
                bf16x8 bf0 = *(const bf16x8*)(wlds + (la ^ sw));         // k 0..31
                bf16x8 bf1 = *(const bf16x8*)(wlds + ((la + 64) ^ sw));  // k 32..63
                f32x4 ci;
                float b0 = bv[n2][ot];
                ci[0] = b0; ci[1] = b0; ci[2] = b0; ci[3] = b0;
                aa[ot] = __builtin_amdgcn_mfma_f32_16x16x32_bf16(af[n2][0], bf0, ci,     0, 0, 0);
                aa[ot] = __builtin_amdgcn_mfma_f32_16x16x32_bf16(af[n2][1], bf1, aa[ot], 0, 0, 0);
            }
            // store: both 64 B o-halves of this block's 128 B span back-to-back
            #pragma unroll
            for (int r = 0; r < 4; ++r) {
                int b = bt * 16 + kg * 4 + r;
                float* op = out + ((size_t)b * N_TOT + n) * O_DIM + o0 + col;
                op[0]  = aa[0][r];
                op[16] = aa[1][r];
            }
        }
    }
}

extern "C" void kernel_launch(void* const* d_in, const int* in_sizes, int n_in,
                              void* d_out, int out_size, void* d_ws, size_t ws_size,
                              hipStream_t stream) {
    const float* x  = (const float*)d_in[0];
    const float* w1 = (const float*)d_in[1];
    const float* b1 = (const float*)d_in[2];
    float* out = (float*)d_out;
    superlinear_mfma<<<dim3(1024), dim3(256), 0, stream>>>(x, w1, b1, out);
}

// Round 9
// 35.771 us; speedup vs baseline: 1.0143x; 1.0143x over previous
//
#include <hip/hip_runtime.h>
#include <hip/hip_bf16.h>

#define N_TOT 2048
#define M_DIM 64
#define O_DIM 128
#define NT 16   // neurons per block: 16 x 4B = one full 64B w1 line per (m,o)
#define OC 64   // o-columns per block

typedef __bf16 bf16x8 __attribute__((ext_vector_type(8)));
typedef float f32x4 __attribute__((ext_vector_type(4)));

// Grid 256 = 128 n-groups x 2 o-halves; 512 thr (8 waves). Each staging
// lane-quad consumes a FULL 64B w1 line (NT=16) -> w1 through-CU traffic
// halves vs NT=8 (the modeled cause of the 35.5us plateau). w1 gathered
// exactly once device-wide; x re-read x2 by o-siblings on the same XCD (L2).
// r7 chassis: 4 o-chunks of 16 cols, triple-buffered 3x32KiB, ds_write of
// chunk c+1 waits on loads issued a full iteration earlier, lgkm-only
// barriers, swizzle applied last, paired 128B-row stores after odd chunks.
__global__ __launch_bounds__(512, 2) void superlinear_mfma(
    const float* __restrict__ x, const float* __restrict__ w1,
    const float* __restrict__ b1, float* __restrict__ out)
{
    __shared__ unsigned char wlds[3 * 32768];  // 3 buffers: [nn16][ol16][k64] bf16

    const int tid  = threadIdx.x;
    const int lane = tid & 63;
    const int wave = tid >> 6;   // 0..7; wave owns neurons wave*2, wave*2+1

    // XCD swizzle (256 % 8 == 0 -> bijective). The 2 o-halves of an n-group
    // are dispatch-adjacent on one XCD -> shared x rows hit that XCD's L2.
    const int bid  = blockIdx.x;
    const int swz  = (bid & 7) * 32 + (bid >> 3);
    const int ngrp = swz >> 1;
    const int oh   = swz & 1;
    const int n0   = ngrp * NT;
    const int o0   = oh * OC;

    const int col = lane & 15;   // o-local (and b-row) index within 16-tile
    const int kg  = lane >> 4;   // k-group (8 bf16)

    // staging decomposition: thread -> (n-quad, o-local in chunk, 8 m-rows)
    const int q    = tid & 3;            // 16B quarter of the 64B n-line
    const int ol   = (tid >> 2) & 15;    // o within chunk
    const int mseg = tid >> 6;           // m-rows mseg*8 .. +7

    const size_t MSTR = (size_t)O_DIM * N_TOT;   // w1 m-stride (floats)

    auto stage_issue = [&](int c, float4* r) {
        const float* gp = w1 + ((size_t)(mseg * 8) * O_DIM + (o0 + c * 16 + ol)) * N_TOT
                             + n0 + q * 4;
        #pragma unroll
        for (int mm = 0; mm < 8; ++mm)
            r[mm] = *(const float4*)(gp + (size_t)mm * MSTR);
    };
    // buffer layout: nn*2048 + ol*128 + k*2 bytes, swizzle ^= (ol&7)<<4
    auto stage_write = [&](int c, const float4* r) {
        unsigned base = (unsigned)(c % 3) * 32768u;
        #pragma unroll
        for (int j = 0; j < 4; ++j) {
            int nn = q * 4 + j;
            bf16x8 v;
            #pragma unroll
            for (int mm = 0; mm < 8; ++mm)
                v[mm] = (__bf16)(((const float*)&r[mm])[j]);
            unsigned addr = (unsigned)(nn * 2048 + ol * 128 + mseg * 16);
            addr ^= (unsigned)((ol & 7) << 4);
            *(bf16x8*)(wlds + base + addr) = v;
        }
    };

    // ---- Prologue ----
    float4 srA[8], srB[8];
    stage_issue(0, srA);                 // oldest in vm queue -> drains first

    // x loads (A operand): 2 neurons x 64 b-rows, both k-chunks
    float4 xr[2][4][4];                  // [n2][bt][kc*2+h]
    #pragma unroll
    for (int n2 = 0; n2 < 2; ++n2)
        #pragma unroll
        for (int bt = 0; bt < 4; ++bt) {
            int b = bt * 16 + col;
            int n = n0 + wave * 2 + n2;
            const float* xp = x + ((size_t)b * N_TOT + n) * M_DIM + kg * 8;
            xr[n2][bt][0] = *(const float4*)xp;
            xr[n2][bt][1] = *(const float4*)(xp + 4);
            xr[n2][bt][2] = *(const float4*)(xp + 32);
            xr[n2][bt][3] = *(const float4*)(xp + 36);
        }
    // bias: 2 neurons x 4 o-tiles of this block's 64-col range
    float bv[2][4];
    #pragma unroll
    for (int n2 = 0; n2 < 2; ++n2)
        #pragma unroll
        for (int c = 0; c < 4; ++c)
            bv[n2][c] = b1[(size_t)(n0 + wave * 2 + n2) * O_DIM + o0 + c * 16 + col];

    stage_issue(1, srB);                 // chunk 1 into flight behind x

    stage_write(0, srA);                 // waits only chunk-0 loads

    bf16x8 af[2][2][4];                  // [n2][kc][bt], converted during drain
    #pragma unroll
    for (int n2 = 0; n2 < 2; ++n2)
        #pragma unroll
        for (int kc = 0; kc < 2; ++kc)
            #pragma unroll
            for (int bt = 0; bt < 4; ++bt) {
                const float* lp = (const float*)&xr[n2][bt][kc * 2 + 0];
                const float* hp = (const float*)&xr[n2][bt][kc * 2 + 1];
                bf16x8 v;
                #pragma unroll
                for (int t = 0; t < 4; ++t) {
                    v[t]     = (__bf16)lp[t];
                    v[4 + t] = (__bf16)hp[t];
                }
                af[n2][kc][bt] = v;
            }

    asm volatile("s_waitcnt lgkmcnt(0)" ::: "memory");
    __builtin_amdgcn_s_barrier();
    __builtin_amdgcn_sched_barrier(0);

    // ---- Main loop: 4 chunks of 16 o-columns ----
    const unsigned sw = (unsigned)(col & 7) << 4;
    f32x4 accP[2][4];                    // even chunk's acc, stored with odd's
    #pragma unroll
    for (int c = 0; c < 4; ++c) {
        if (c < 2) stage_issue(c + 2, (c & 1) ? srB : srA);  // 1 iter ahead

        unsigned base = (unsigned)(c % 3) * 32768u;
        f32x4 acc[2][4];
        #pragma unroll
        for (int n2 = 0; n2 < 2; ++n2) {
            int nn = wave * 2 + n2;
            // logical addr first (bit 6 clean: kg*16 <= 48), swizzle LAST
            unsigned la = (unsigned)(nn * 2048 + col * 128 + kg * 16);
            bf16x8 bf0 = *(const bf16x8*)(wlds + base + (la ^ sw));         // k 0..31
            bf16x8 bf1 = *(const bf16x8*)(wlds + base + ((la + 64) ^ sw));  // k 32..63
            f32x4 ci;
            float b0 = bv[n2][c];
            ci[0] = b0; ci[1] = b0; ci[2] = b0; ci[3] = b0;
            #pragma unroll
            for (int bt = 0; bt < 4; ++bt) {
                acc[n2][bt] = __builtin_amdgcn_mfma_f32_16x16x32_bf16(af[n2][0][bt], bf0, ci,          0, 0, 0);
                acc[n2][bt] = __builtin_amdgcn_mfma_f32_16x16x32_bf16(af[n2][1][bt], bf1, acc[n2][bt], 0, 0, 0);
            }
        }

        // ds_write chunk c+1 (its loads were issued one full iteration ago)
        if (c < 3) stage_write(c + 1, (c & 1) ? srA : srB);

        if (c & 1) {
            // store chunk pair (c-1, c): 128B per (b,n)-row back-to-back
            #pragma unroll
            for (int n2 = 0; n2 < 2; ++n2) {
                int n = n0 + wave * 2 + n2;
                #pragma unroll
                for (int bt = 0; bt < 4; ++bt)
                    #pragma unroll
                    for (int r = 0; r < 4; ++r) {
                        int b = bt * 16 + kg * 4 + r;
                        float* op = out + ((size_t)b * N_TOT + n) * O_DIM
                                        + o0 + (c - 1) * 16 + col;
                        op[0]  = accP[n2][bt][r];
                        op[16] = acc[n2][bt][r];
                    }
            }
        } else {
            #pragma unroll
            for (int n2 = 0; n2 < 2; ++n2)
                #pragma unroll
                for (int bt = 0; bt < 4; ++bt)
                    accP[n2][bt] = acc[n2][bt];
        }

        if (c < 3) {
            asm volatile("s_waitcnt lgkmcnt(0)" ::: "memory");
            __builtin_amdgcn_s_barrier();
            __builtin_amdgcn_sched_barrier(0);
        }
    }
}

extern "C" void kernel_launch(void* const* d_in, const int* in_sizes, int n_in,
                              void* d_out, int out_size, void* d_ws, size_t ws_size,
                              hipStream_t stream) {
    const float* x  = (const float*)d_in[0];
    const float* w1 = (const float*)d_in[1];
    const float* b1 = (const float*)d_in[2];
    float* out = (float*)d_out;
    superlinear_mfma<<<dim3(256), dim3(512), 0, stream>>>(x, w1, b1, out);
}